// Round 7
// baseline (667.739 us; speedup 1.0000x reference)
//
#include <hip/hip_runtime.h>
#include <hip/hip_bf16.h>

// Problem constants (fixed by reference setup_inputs)
#define NBATCH 128
#define TLEN   2048
#define FDIM   88
#define WIN    64
#define TT     512           // time-tile per block: ONE 8-wave block per CU
#define FRAMES (TT + WIN)    // 576 staged frames
#define LSTR   100           // frame stride in bf16; 200B -> verified conflict-free (R2: BANK_CONFLICT=0)
#define BSLICE (18 * 512)    // 9216 elems per tau slice of fragment-packed Wt
#define XS_BYTES (FRAMES * LSTR * 2)   // 115,200 B dynamic LDS

typedef __attribute__((ext_vector_type(8))) short short8;   // 8 x bf16 (4 VGPR) MFMA A/B frag
typedef __attribute__((ext_vector_type(4))) short short4v;  // 8B LDS store
typedef __attribute__((ext_vector_type(4))) float floatx4;  // MFMA C/D frag

static __device__ __forceinline__ unsigned short f2bf(float f) {
    union { float f; unsigned int u; } a; a.f = f;
    unsigned int u = a.u;
    u += 0x7fffu + ((u >> 16) & 1u);   // round-to-nearest-even
    return (unsigned short)(u >> 16);
}

// Repack W (FDIM x WIN*FDIM, fp32) -> fragment-packed bf16:
//   Wt[tau][kk(0..2)][n_t(0..5)][lane(0..63)][j(0..7)]
// B-fragment for (tau,kk,n_t) is a contiguous 1KB block;
//   value = W[n][tau*88 + k], n = n_t*16 + (lane&15), k = kk*32 + (lane>>4)*8 + j
// (zero-padded where n>=88 or k>=88).
__global__ void prep_w(const float* __restrict__ W, unsigned short* __restrict__ Wt) {
    int idx = blockIdx.x * blockDim.x + threadIdx.x;
    if (idx >= WIN * BSLICE) return;
    int j    = idx & 7;
    int lane = (idx >> 3) & 63;
    int rest = idx >> 9;                             // (tau*3 + kk)*6 + n_t
    int nt   = rest % 6;
    int kkt  = rest / 6;
    int kk   = kkt % 3;
    int tau  = kkt / 3;
    int n = nt * 16 + (lane & 15);
    int k = kk * 32 + (lane >> 4) * 8 + j;
    float v = 0.f;
    if (n < FDIM && k < FDIM) v = W[n * (WIN * FDIM) + tau * FDIM + k];
    Wt[idx] = f2bf(v);
}

// out[nb, t0+tr, fo] = b[fo] + sum_{tau,fi} x[nb, t0+tr-64+tau, fi] * W[fo, tau*88+fi]
// 8 waves, each owns 64 rows (time) x 96 cols (f_out) -- R1's per-wave structure
// (best measured: 42% MfmaUtil) with ONE block per CU so the 18KB Wt tau-slice
// owns the whole 32KB L1 (2 blocks/CU at independent tau = 36KB thrash).
// Loads stay inline/compiler-scheduled (R4/R6 proved hand-pipelining regresses).
// A raw s_barrier every 8 tau bounds wave drift without starving load hoisting.
__global__ __launch_bounds__(512, 2) void conv_mfma(
    const float* __restrict__ x, const unsigned short* __restrict__ Wt,
    const float* __restrict__ bias, float* __restrict__ out)
{
    extern __shared__ unsigned short xs[];          // 115,200 B -> 1 block/CU

    const int tb  = blockIdx.x;
    const int nb  = blockIdx.y;
    const int t0  = tb * TT;
    const int tid = threadIdx.x;

    const int wave = tid >> 6;         // 0..7
    const int lane = tid & 63;
    const int m    = lane & 15;        // MFMA row/col-in-frag index
    const int quad = lane >> 4;        // k-subgroup
    const int wrow = wave * 64;        // wave row offset (time)

    // ---- stage x tile: frames [t0-64, t0+TT-1], bf16, zero-padded (time & feature) ----
    const float* xn = x + (size_t)nb * TLEN * FDIM;
    for (int idx = tid; idx < FRAMES * 25; idx += 512) {   // 25 float4-slots (22 real, 3 zero-pad)
        int i = idx / 25;
        int c = idx % 25;
        int g = t0 - WIN + i;
        short4v v = (short4v){0, 0, 0, 0};
        if (c < 22 && g >= 0) {
            float4 f = *((const float4*)(xn + (size_t)g * FDIM) + c);
            v.x = (short)f2bf(f.x); v.y = (short)f2bf(f.y);
            v.z = (short)f2bf(f.z); v.w = (short)f2bf(f.w);
        }
        *(short4v*)&xs[i * LSTR + c * 4] = v;
    }
    __syncthreads();

    floatx4 acc[4][6] = {};            // [m_t 16-row tiles][n_t 16-col tiles]
    const int a_base = (wrow + m) * LSTR + quad * 8;

    for (int to = 0; to < WIN; to += 8) {
        __builtin_amdgcn_s_barrier();          // keep 8 waves on the same Wt slice (L1)
        for (int tau = to; tau < to + 8; ++tau) {
            const unsigned short* wt_tau = Wt + (size_t)tau * BSLICE + lane * 8;
            const int a_tau = a_base + tau * LSTR;
            #pragma unroll
            for (int kk = 0; kk < 3; ++kk) {
                short8 bf[6];
                #pragma unroll
                for (int n_t = 0; n_t < 6; ++n_t)
                    bf[n_t] = *(const short8*)(wt_tau + (kk * 6 + n_t) * 512);
                short8 af[4];
                #pragma unroll
                for (int m_t = 0; m_t < 4; ++m_t)
                    af[m_t] = *(const short8*)&xs[a_tau + m_t * 16 * LSTR + kk * 32];
                __builtin_amdgcn_s_setprio(1);
                #pragma unroll
                for (int m_t = 0; m_t < 4; ++m_t)
                    #pragma unroll
                    for (int n_t = 0; n_t < 6; ++n_t)
                        acc[m_t][n_t] = __builtin_amdgcn_mfma_f32_16x16x32_bf16(
                            af[m_t], bf[n_t], acc[m_t][n_t], 0, 0, 0);
                __builtin_amdgcn_s_setprio(0);
            }
        }
    }

    // ---- epilogue: D layout col=lane&15, row=quad*4+reg; add bias; write both tuple halves ----
    float bv[6];
    #pragma unroll
    for (int n_t = 0; n_t < 6; ++n_t) {
        int c = n_t * 16 + m;
        bv[n_t] = (c < FDIM) ? bias[c] : 0.f;
    }
    const size_t half = (size_t)NBATCH * TLEN * FDIM;
    #pragma unroll
    for (int n_t = 0; n_t < 6; ++n_t) {
        int c = n_t * 16 + m;
        if (c >= FDIM) continue;
        #pragma unroll
        for (int m_t = 0; m_t < 4; ++m_t) {
            #pragma unroll
            for (int reg = 0; reg < 4; ++reg) {
                int tr = wrow + m_t * 16 + quad * 4 + reg;
                size_t off = ((size_t)nb * TLEN + (t0 + tr)) * FDIM + c;
                float v = acc[m_t][n_t][reg] + bv[n_t];
                out[off] = v;
                out[half + off] = v;
            }
        }
    }
}

extern "C" void kernel_launch(void* const* d_in, const int* in_sizes, int n_in,
                              void* d_out, int out_size, void* d_ws, size_t ws_size,
                              hipStream_t stream) {
    const float* x = (const float*)d_in[0];
    const float* W = (const float*)d_in[1];
    const float* b = (const float*)d_in[2];
    float* out = (float*)d_out;
    unsigned short* Wt = (unsigned short*)d_ws;   // 64*18*512*2 = 1,179,648 B

    // allow 115.2 KB dynamic LDS (static __shared__ caps at 64 KB)
    static bool attr_set = false;
    if (!attr_set) {
        hipFuncSetAttribute((const void*)conv_mfma,
                            hipFuncAttributeMaxDynamicSharedMemorySize, XS_BYTES);
        attr_set = true;
    }

    prep_w<<<(WIN * BSLICE + 255) / 256, 256, 0, stream>>>(W, Wt);
    dim3 grid(TLEN / TT, NBATCH);
    conv_mfma<<<grid, 512, XS_BYTES, stream>>>(x, Wt, b, out);
}

// Round 8
// 500.325 us; speedup vs baseline: 1.3346x; 1.3346x over previous
//
#include <hip/hip_runtime.h>
#include <hip/hip_bf16.h>

// Problem constants (fixed by reference setup_inputs)
#define NBATCH 128
#define TLEN   2048
#define FDIM   88
#define WIN    64
#define TT     128           // time-tile per block -> 38.4 KB LDS -> 4 blocks/CU -> 4 waves/SIMD
#define FRAMES (TT + WIN)    // 192 staged frames
#define LSTR   100           // frame stride in bf16; 200B -> verified conflict-free (R2: BANK_CONFLICT=0)
#define BSLICE (18 * 512)    // 9216 elems per tau slice of fragment-packed Wt

typedef __attribute__((ext_vector_type(8))) short short8;   // 8 x bf16 (4 VGPR) MFMA A/B frag
typedef __attribute__((ext_vector_type(4))) short short4v;  // 8B LDS store
typedef __attribute__((ext_vector_type(4))) float floatx4;  // MFMA C/D frag

static __device__ __forceinline__ unsigned short f2bf(float f) {
    union { float f; unsigned int u; } a; a.f = f;
    unsigned int u = a.u;
    u += 0x7fffu + ((u >> 16) & 1u);   // round-to-nearest-even
    return (unsigned short)(u >> 16);
}

// Repack W (FDIM x WIN*FDIM, fp32) -> fragment-packed bf16:
//   Wt[tau][kk(0..2)][n_t(0..5)][lane(0..63)][j(0..7)]
// B-fragment for (tau,kk,n_t) is a contiguous 1KB block;
//   value = W[n][tau*88 + k], n = n_t*16 + (lane&15), k = kk*32 + (lane>>4)*8 + j
// (zero-padded where n>=88 or k>=88).
__global__ void prep_w(const float* __restrict__ W, unsigned short* __restrict__ Wt) {
    int idx = blockIdx.x * blockDim.x + threadIdx.x;
    if (idx >= WIN * BSLICE) return;
    int j    = idx & 7;
    int lane = (idx >> 3) & 63;
    int rest = idx >> 9;                             // (tau*3 + kk)*6 + n_t
    int nt   = rest % 6;
    int kkt  = rest / 6;
    int kk   = kkt % 3;
    int tau  = kkt / 3;
    int n = nt * 16 + (lane & 15);
    int k = kk * 32 + (lane >> 4) * 8 + j;
    float v = 0.f;
    if (n < FDIM && k < FDIM) v = W[n * (WIN * FDIM) + tau * FDIM + k];
    Wt[idx] = f2bf(v);
}

// out[nb, t0+tr, fo] = b[fo] + sum_{tau,fi} x[nb, t0+tr-64+tau, fi] * W[fo, tau*88+fi]
// 4 waves (2 row x 2 col), each wave owns 64 rows (time) x 48 cols (f_out).
// R1's scheduling style EXACTLY (inline compiler-scheduled B loads, no K-loop
// barriers) -- every deviation regressed (R2/R4/R6/R7). Single change vs R1:
// smaller LDS tile -> 4 blocks/CU -> 4 waves/SIMD (2x the latency-hiding TLP;
// occupancy was the one untested knob, VGPRs were never the limit).
__global__ __launch_bounds__(256, 4) void conv_mfma(
    const float* __restrict__ x, const unsigned short* __restrict__ Wt,
    const float* __restrict__ bias, float* __restrict__ out)
{
    __shared__ unsigned short xs[FRAMES * LSTR];    // 38,400 B -> 4 blocks/CU

    const int tb  = blockIdx.x;
    const int nb  = blockIdx.y;
    const int t0  = tb * TT;
    const int tid = threadIdx.x;

    // ---- stage x tile: frames [t0-64, t0+TT-1], bf16, zero-padded (time & feature) ----
    const float* xn = x + (size_t)nb * TLEN * FDIM;
    for (int idx = tid; idx < FRAMES * 25; idx += 256) {   // 25 float4-slots (22 real, 3 zero-pad)
        int i = idx / 25;
        int c = idx % 25;
        int g = t0 - WIN + i;
        short4v v = (short4v){0, 0, 0, 0};
        if (c < 22 && g >= 0) {
            float4 f = *((const float4*)(xn + (size_t)g * FDIM) + c);
            v.x = (short)f2bf(f.x); v.y = (short)f2bf(f.y);
            v.z = (short)f2bf(f.z); v.w = (short)f2bf(f.w);
        }
        *(short4v*)&xs[i * LSTR + c * 4] = v;
    }
    __syncthreads();

    // ---- wave tiling: 2x2 waves, each 64 rows x 48 cols ----
    const int wave = tid >> 6;
    const int lane = tid & 63;
    const int m    = lane & 15;        // MFMA row/col-in-frag index
    const int quad = lane >> 4;        // k-subgroup
    const int wrow = (wave >> 1) * 64; // wave row offset (time)
    const int wcol = (wave & 1) * 48;  // wave col offset (f_out)
    const int nt0  = (wave & 1) * 3;   // first n_t slot in the tau slice

    floatx4 acc[4][3] = {};            // [m_t 16-row tiles][n_t 16-col tiles]
    const int a_base = (wrow + m) * LSTR + quad * 8;

    for (int tau = 0; tau < WIN; ++tau) {
        const unsigned short* wt_tau = Wt + (size_t)tau * BSLICE + (size_t)(nt0 * 512) + lane * 8;
        const int a_tau = a_base + tau * LSTR;
        #pragma unroll
        for (int kk = 0; kk < 3; ++kk) {
            short8 bf[3];
            #pragma unroll
            for (int n_t = 0; n_t < 3; ++n_t)
                bf[n_t] = *(const short8*)(wt_tau + (kk * 6 + n_t) * 512);
            short8 af[4];
            #pragma unroll
            for (int m_t = 0; m_t < 4; ++m_t)
                af[m_t] = *(const short8*)&xs[a_tau + m_t * 16 * LSTR + kk * 32];
            __builtin_amdgcn_s_setprio(1);
            #pragma unroll
            for (int m_t = 0; m_t < 4; ++m_t)
                #pragma unroll
                for (int n_t = 0; n_t < 3; ++n_t)
                    acc[m_t][n_t] = __builtin_amdgcn_mfma_f32_16x16x32_bf16(
                        af[m_t], bf[n_t], acc[m_t][n_t], 0, 0, 0);
            __builtin_amdgcn_s_setprio(0);
        }
    }

    // ---- epilogue: D layout col=lane&15, row=quad*4+reg; add bias; write both tuple halves ----
    float bv[3];
    #pragma unroll
    for (int n_t = 0; n_t < 3; ++n_t) {
        int c = wcol + n_t * 16 + m;
        bv[n_t] = (c < FDIM) ? bias[c] : 0.f;
    }
    const size_t half = (size_t)NBATCH * TLEN * FDIM;
    #pragma unroll
    for (int n_t = 0; n_t < 3; ++n_t) {
        int c = wcol + n_t * 16 + m;
        if (c >= FDIM) continue;
        #pragma unroll
        for (int m_t = 0; m_t < 4; ++m_t) {
            #pragma unroll
            for (int reg = 0; reg < 4; ++reg) {
                int tr = wrow + m_t * 16 + quad * 4 + reg;
                size_t off = ((size_t)nb * TLEN + (t0 + tr)) * FDIM + c;
                float v = acc[m_t][n_t][reg] + bv[n_t];
                out[off] = v;
                out[half + off] = v;
            }
        }
    }
}

extern "C" void kernel_launch(void* const* d_in, const int* in_sizes, int n_in,
                              void* d_out, int out_size, void* d_ws, size_t ws_size,
                              hipStream_t stream) {
    const float* x = (const float*)d_in[0];
    const float* W = (const float*)d_in[1];
    const float* b = (const float*)d_in[2];
    float* out = (float*)d_out;
    unsigned short* Wt = (unsigned short*)d_ws;   // 64*18*512*2 = 1,179,648 B

    prep_w<<<(WIN * BSLICE + 255) / 256, 256, 0, stream>>>(W, Wt);
    dim3 grid(TLEN / TT, NBATCH);
    conv_mfma<<<grid, 256, 0, stream>>>(x, Wt, b, out);
}